// Round 5
// baseline (341.900 us; speedup 1.0000x reference)
//
#include <hip/hip_runtime.h>
#include <stdint.h>

#define WW 1024
#define HH 1024
#define NB 4
#define HW (HH * WW)
#define NPIX (NB * HW)        // 4194304
#define NTILES 4096           // 32x32 tiles per input
#define INVALID 0xFFFFFFFFu
#define RS 8                  // rows per k_open block

// counters: bank t at c[t*8]:
// [0]=min_bits [1]=max_bits [2]=numFg [3]=local_components [4]=root0 [5]=border_links

__global__ void k_zero(uint32_t* c) {
    c[0] = 0x7F800000u; c[1] = 0; c[2] = 0; c[3] = 0; c[4] = 0; c[5] = 0;
    c[8] = 0x7F800000u; c[9] = 0; c[10] = 0; c[11] = 0; c[12] = 0; c[13] = 0;
}

// ---- fused opening (cross erode+dilate) + per-input min/max, row-sweep -----
__global__ void k_open(const float* __restrict__ in0, const float* __restrict__ in1,
                       float* __restrict__ out0, float* __restrict__ out1,
                       uint32_t* cbase) {
    int t6 = blockIdx.x >> 9;            // input index
    int r  = blockIdx.x & 511;
    int b  = r >> 7;
    int y0 = (r & 127) * RS;
    int t  = threadIdx.x;
    const float* in = t6 ? in1 : in0;
    float* out      = t6 ? out1 : out0;
    uint32_t* c     = cbase + t6 * 8;
    const float4* inb = (const float4*)(in + (size_t)b * HW);
    float4* outb      = (float4*)(out + (size_t)b * HW);

    float4 A[RS + 4];
    #pragma unroll
    for (int j = 0; j < RS + 4; j++) {
        int iy = y0 - 2 + j;
        if (iy >= 0 && iy < HH) A[j] = inb[iy * 256 + t];
        else A[j] = make_float4(1e10f, 1e10f, 1e10f, 1e10f);  // erosion pad
    }

    __shared__ float sx[RS + 2][258];
    __shared__ float sw[RS + 2][258];
    #pragma unroll
    for (int rr = 0; rr < RS + 2; rr++) { sx[rr][t + 1] = A[rr + 1].x; sw[rr][t + 1] = A[rr + 1].w; }
    if (t < RS + 2) { sw[t][0] = 1e10f; sx[t][257] = 1e10f; }
    __syncthreads();

    float4 E[RS + 2];
    #pragma unroll
    for (int rr = 0; rr < RS + 2; rr++) {
        int ey = y0 - 1 + rr;
        float lw = sw[rr][t], rw = sx[rr][t + 2];
        float4 v = A[rr + 1];
        float hx = fminf(fminf(lw, v.x), v.y);
        float hy = fminf(fminf(v.x, v.y), v.z);
        float hz = fminf(fminf(v.y, v.z), v.w);
        float hw = fminf(fminf(v.z, v.w), rw);
        float4 e;
        e.x = fminf(hx, fminf(A[rr].x, A[rr + 2].x));
        e.y = fminf(hy, fminf(A[rr].y, A[rr + 2].y));
        e.z = fminf(hz, fminf(A[rr].z, A[rr + 2].z));
        e.w = fminf(hw, fminf(A[rr].w, A[rr + 2].w));
        if (ey < 0 || ey >= HH) e = make_float4(-1e10f, -1e10f, -1e10f, -1e10f);
        E[rr] = e;
    }
    __syncthreads();

    #pragma unroll
    for (int d = 0; d < RS; d++) { sx[d][t + 1] = E[d + 1].x; sw[d][t + 1] = E[d + 1].w; }
    if (t < RS) { sw[t][0] = -1e10f; sx[t][257] = -1e10f; }
    __syncthreads();

    float lmin = __uint_as_float(0x7F800000u);
    float lmax = 0.0f;
    #pragma unroll
    for (int d = 0; d < RS; d++) {
        float lw = sw[d][t], rw = sx[d][t + 2];
        float4 v = E[d + 1];
        float hx = fmaxf(fmaxf(lw, v.x), v.y);
        float hy = fmaxf(fmaxf(v.x, v.y), v.z);
        float hz = fmaxf(fmaxf(v.y, v.z), v.w);
        float hw = fmaxf(fmaxf(v.z, v.w), rw);
        float4 o;
        o.x = fmaxf(hx, fmaxf(E[d].x, E[d + 2].x));
        o.y = fmaxf(hy, fmaxf(E[d].y, E[d + 2].y));
        o.z = fmaxf(hz, fmaxf(E[d].z, E[d + 2].z));
        o.w = fmaxf(hw, fmaxf(E[d].w, E[d + 2].w));
        outb[(y0 + d) * 256 + t] = o;
        lmin = fminf(lmin, fminf(fminf(o.x, o.y), fminf(o.z, o.w)));
        lmax = fmaxf(lmax, fmaxf(fmaxf(o.x, o.y), fmaxf(o.z, o.w)));
    }
    for (int off = 32; off > 0; off >>= 1) {
        lmin = fminf(lmin, __shfl_down(lmin, off));
        lmax = fmaxf(lmax, __shfl_down(lmax, off));
    }
    __shared__ float smin[4], smax[4];
    if ((t & 63) == 0) { smin[t >> 6] = lmin; smax[t >> 6] = lmax; }
    __syncthreads();
    if (t == 0) {
        float m0 = fminf(fminf(smin[0], smin[1]), fminf(smin[2], smin[3]));
        float m1 = fmaxf(fmaxf(smax[0], smax[1]), fmaxf(smax[2], smax[3]));
        atomicMin(&c[0], __float_as_uint(m0));  // non-negative floats: bit order == float order
        atomicMax(&c[1], __float_as_uint(m1));
    }
}

// ---------------- LDS union-find (workgroup scope) --------------------------
__device__ __forceinline__ uint32_t lload(uint32_t* lp, uint32_t x) {
    return __hip_atomic_load(&lp[x], __ATOMIC_RELAXED, __HIP_MEMORY_SCOPE_WORKGROUP);
}
__device__ __forceinline__ uint32_t lfind(uint32_t* lp, uint32_t x) {
    uint32_t p = lload(lp, x);
    while (p != x) {
        uint32_t gp = lload(lp, p);
        if (gp != p)
            __hip_atomic_store(&lp[x], gp, __ATOMIC_RELAXED, __HIP_MEMORY_SCOPE_WORKGROUP);
        x = p; p = gp;
    }
    return x;
}
// returns 1 if this call performed the successful root-killing CAS, else 0
__device__ uint32_t lunion(uint32_t* lp, uint32_t a, uint32_t b) {
    uint32_t ra = lfind(lp, a), rb = lfind(lp, b);
    while (ra != rb) {
        uint32_t hi = ra > rb ? ra : rb;
        uint32_t lo = ra ^ rb ^ hi;
        uint32_t old = atomicCAS(&lp[lo], lo, hi);
        if (old == lo) return 1;
        ra = lfind(lp, old);
        rb = lfind(lp, hi);
    }
    return 0;
}

__device__ __forceinline__ int run_len(uint32_t bits) {  // consecutive 1s from bit 0
    return (int)__builtin_ctzll(~(uint64_t)bits);        // safe for bits==0xFFFFFFFF
}

// ---------------- binarize + tile-local run-based CCL (both inputs) ---------
// P stored ONLY for 4-edge band pixels and component-max pixels (all that
// k_border ever reads); interior non-max pixels are never consulted again.
__global__ void k_ccl(const float* __restrict__ op0, const float* __restrict__ op1,
                      uint32_t* __restrict__ P0, uint32_t* __restrict__ P1,
                      uint32_t* cbase) {
    int t6 = blockIdx.x >> 12;
    int tile = blockIdx.x & 4095;
    const float* opened = t6 ? op1 : op0;
    uint32_t* P = t6 ? P1 : P0;
    uint32_t* c = cbase + t6 * 8;

    int b  = tile >> 10;
    int tt = tile & 1023;
    int ty0 = (tt >> 5) << 5;
    int tx0 = (tt & 31) << 5;
    uint32_t base = (uint32_t)b * HW + (uint32_t)ty0 * WW + tx0;

    float mn = __uint_as_float(c[0]);
    float mx = __uint_as_float(c[1]);
    float denom = (mx - mn) + 1e-10f;  // reference association order

    __shared__ uint32_t m[32];
    __shared__ uint32_t lp[1024];
    int trow = threadIdx.x >> 3;        // 0..31
    int tc4  = (threadIdx.x & 7) << 2;  // 0,4,..,28
    const float4* op4 = (const float4*)(opened + base);
    float4 v = op4[trow * 256 + (tc4 >> 2)];   // all tile reads before first barrier
    uint32_t m0 = ((v.x - mn) / denom >= 0.5f) ? 1u : 0u;  // IEEE f32 div
    uint32_t m1 = ((v.y - mn) / denom >= 0.5f) ? 1u : 0u;
    uint32_t m2 = ((v.z - mn) / denom >= 0.5f) ? 1u : 0u;
    uint32_t m3 = ((v.w - mn) / denom >= 0.5f) ? 1u : 0u;
    uint32_t fgcnt = m0 + m1 + m2 + m3;
    uint32_t rowm = (m0 | (m1 << 1) | (m2 << 2) | (m3 << 3)) << tc4;
    rowm |= __shfl_xor(rowm, 1, 8);     // 8 lanes of a row share one group
    rowm |= __shfl_xor(rowm, 2, 8);
    rowm |= __shfl_xor(rowm, 4, 8);
    if ((threadIdx.x & 7) == 0) m[trow] = rowm;
    int li0 = (trow << 5) + tc4;
    #pragma unroll
    for (int j = 0; j < 4; j++) lp[li0 + j] = li0 + j;
    __syncthreads();

    // unions at run-start pixels, one per overlapping run in the row above
    uint32_t links = 0;
    if (trow > 0 && rowm) {
        uint32_t up = m[trow - 1];
        #pragma unroll
        for (int j = 0; j < 4; j++) {
            int lx = tc4 + j;
            if (!((rowm >> lx) & 1u)) continue;
            if (lx > 0 && ((rowm >> (lx - 1)) & 1u)) continue;  // not run start
            int len = run_len(rowm >> lx);
            int e = lx + len - 1;
            int lo = (lx == 0) ? 0 : lx - 1;
            int hi = (e >= 31) ? 31 : e + 1;
            uint32_t hm = (hi == 31) ? 0xFFFFFFFFu : ((1u << (hi + 1)) - 1u);
            uint32_t w = up & hm & ~((1u << lo) - 1u);
            uint32_t repA = ((uint32_t)trow << 5) + e;
            while (w) {
                int xs = __builtin_ctz(w);
                int xe = xs + run_len(up >> xs) - 1;  // rep of the full run above
                links += lunion(lp, repA, ((uint32_t)(trow - 1) << 5) + (uint32_t)xe);
                w = (xe >= 31) ? 0u : (w & ~((1u << (xe + 1)) - 1u));
            }
        }
    }
    __syncthreads();

    // pixel 0 / label-0 case: component max == 0 iff pixel 0 is an isolated
    // fg singleton; decidable here (all its neighbors are intra-tile)
    if (tile == 0 && threadIdx.x == 0) {
        if ((rowm & 1u) && !(rowm & 2u) && lp[0] == 0u) atomicOr(&c[4], 1u);
    }

    // flatten: store P only where k_border may read (band + component maxes)
    int laste = -1; uint32_t lastg = 0;
    #pragma unroll
    for (int j = 0; j < 4; j++) {
        int lx = tc4 + j;
        uint32_t gi = base + (uint32_t)trow * WW + (uint32_t)lx;
        bool fg = (rowm >> lx) & 1u;
        uint32_t g = INVALID;
        if (fg) {
            int e = lx + run_len(rowm >> lx) - 1;
            if (e == laste) g = lastg;
            else {
                uint32_t r = lfind(lp, ((uint32_t)trow << 5) + (uint32_t)e);
                lastg = base + (r >> 5) * WW + (r & 31);
                laste = e;
                g = lastg;
            }
        }
        bool band = (trow == 0) | (trow == 31) | (lx == 0) | (lx == 31);
        if (band || (fg && g == gi)) P[gi] = g;
    }

    // packed block reduction: fg(12b) | runs(10b) | links(10b)
    uint32_t runs = ((threadIdx.x & 7) == 0) ? (uint32_t)__popc(rowm & ~(rowm << 1)) : 0u;
    uint32_t pk = (fgcnt << 20) | (runs << 10) | links;
    for (int off = 32; off > 0; off >>= 1) pk += __shfl_down(pk, off);
    __shared__ uint32_t s[4];
    if ((threadIdx.x & 63) == 0) s[threadIdx.x >> 6] = pk;
    __syncthreads();
    if (threadIdx.x == 0) {
        uint32_t sum = s[0] + s[1] + s[2] + s[3];
        uint32_t fgs = sum >> 20, rns = (sum >> 10) & 1023u, lks = sum & 1023u;
        if (fgs) atomicAdd(&c[2], fgs);
        if (rns - lks) atomicAdd(&c[3], rns - lks);  // tile-local component count
    }
}

// ---------------- global union-find (device scope, cross-XCD safe) ----------
__device__ __forceinline__ uint32_t pload(uint32_t* P, uint32_t x) {
    return __hip_atomic_load(&P[x], __ATOMIC_RELAXED, __HIP_MEMORY_SCOPE_AGENT);
}
__device__ __forceinline__ uint32_t uf_find(uint32_t* P, uint32_t x) {
    uint32_t p = pload(P, x);
    while (p != x) {
        uint32_t gp = pload(P, p);
        if (gp != p)
            __hip_atomic_store(&P[x], gp, __ATOMIC_RELAXED, __HIP_MEMORY_SCOPE_AGENT);
        x = p; p = gp;
    }
    return x;
}
__device__ uint32_t uf_union(uint32_t* P, uint32_t a, uint32_t b) {
    uint32_t ra = uf_find(P, a);
    uint32_t rb = uf_find(P, b);
    while (ra != rb) {
        uint32_t hi = ra > rb ? ra : rb;
        uint32_t lo = ra ^ rb ^ hi;
        uint32_t old = atomicCAS(&P[lo], lo, hi);
        if (old == lo) return 1;  // killed exactly one root
        ra = uf_find(P, old);
        rb = uf_find(P, hi);
    }
    return 0;
}

// border pixels only, both inputs: 96 candidates/tile (lx==0, lx==31, ly==31)
__global__ void k_border(uint32_t* P0, uint32_t* P1, uint32_t* cbase) {
    int t6 = (blockIdx.x >= 1536);
    uint32_t* P = t6 ? P1 : P0;
    uint32_t* c = cbase + t6 * 8;
    int tid = (blockIdx.x - (t6 ? 1536 : 0)) * 256 + threadIdx.x;
    int tile = tid / 96;
    int k = tid - tile * 96;
    int b  = tile >> 10;
    int tt = tile & 1023;
    int ty0 = (tt >> 5) << 5;
    int tx0 = (tt & 31) << 5;
    int g = k >> 5, o = k & 31;
    int ly, lx;
    if (g == 0)      { ly = o;  lx = 0; }
    else if (g == 1) { ly = o;  lx = 31; }
    else             { ly = 31; lx = o; }   // corners duplicated: link-count safe (CAS unique)
    int x = tx0 + lx, y = ty0 + ly;
    int i = b * HW + y * WW + x;
    uint32_t links = 0;
    if (P[i] != INVALID) {
        bool xe = (x < WW - 1), ys = (y < HH - 1);
        if (lx == 31 && xe && P[i + 1] != INVALID) links += uf_union(P, i, i + 1);
        if (ys) {
            bool cS = (ly == 31);
            if (cS && P[i + WW] != INVALID)                            links += uf_union(P, i, i + WW);
            if ((cS || lx == 0)  && x > 0 && P[i + WW - 1] != INVALID) links += uf_union(P, i, i + WW - 1);
            if ((cS || lx == 31) && xe    && P[i + WW + 1] != INVALID) links += uf_union(P, i, i + WW + 1);
        }
    }
    for (int off = 32; off > 0; off >>= 1) links += __shfl_down(links, off);
    __shared__ uint32_t s[4];
    if ((threadIdx.x & 63) == 0) s[threadIdx.x >> 6] = links;
    __syncthreads();
    if (threadIdx.x == 0) {
        uint32_t sum = s[0] + s[1] + s[2] + s[3];
        if (sum) atomicAdd(&c[5], sum);
    }
}

__global__ void k_final(const uint32_t* __restrict__ c, float* __restrict__ out) {
    uint32_t nf0 = c[2],  lc0 = c[3],  z0 = c[4],  gl0 = c[5];
    uint32_t nf1 = c[10], lc1 = c[11], z1 = c[12], gl1 = c[13];
    uint32_t roots0 = lc0 - gl0;   // total final roots (incl. a pixel-0 singleton)
    uint32_t roots1 = lc1 - gl1;
    float ccs  = (float)(roots0 - z0 + ((nf0 < (uint32_t)NPIX || z0) ? 1u : 0u));
    float ccsg = (float)(roots1 - z1 + ((nf1 < (uint32_t)NPIX || z1) ? 1u : 0u));
    out[0] = fabsf(ccsg - ccs) / (float)nf1;   // all exact ints < 2^24
}

extern "C" void kernel_launch(void* const* d_in, const int* in_sizes, int n_in,
                              void* d_out, int out_size, void* d_ws, size_t ws_size,
                              hipStream_t stream) {
    const float* img = (const float*)d_in[0];
    const float* lab = (const float*)d_in[1];
    float* out = (float*)d_out;
    char* ws = (char*)d_ws;

    float* buf0 = (float*)ws;                                   // 16 MB img: opened -> P (in place)
    float* buf1 = (float*)(ws + (size_t)NPIX * sizeof(float));  // 16 MB lab: opened -> P
    uint32_t* cnt = (uint32_t*)(ws + (size_t)2 * NPIX * sizeof(float));
    uint32_t* P0 = (uint32_t*)buf0;
    uint32_t* P1 = (uint32_t*)buf1;

    k_zero<<<1, 1, 0, stream>>>(cnt);
    k_open<<<2 * NB * (HH / RS), 256, 0, stream>>>(img, lab, buf0, buf1, cnt);
    k_ccl<<<2 * NTILES, 256, 0, stream>>>(buf0, buf1, P0, P1, cnt);
    k_border<<<2 * (NTILES * 96) / 256, 256, 0, stream>>>(P0, P1, cnt);
    k_final<<<1, 1, 0, stream>>>(cnt, out);
}

// Round 6
// 302.515 us; speedup vs baseline: 1.1302x; 1.1302x over previous
//
#include <hip/hip_runtime.h>
#include <stdint.h>

#define WW 1024
#define HH 1024
#define NB 4
#define HW (HH * WW)
#define NPIX (NB * HW)        // 4194304
#define NTILES 4096           // 32x32 tiles per input
#define INVALID 0xFFFFFFFFu
#define RS 8                  // rows per k_open block

// counter layout (uint32 words), one 64B line per bank:
//   bank t at c[t*16]: [0]=min_bits [1]=max_bits [2]=numFg [3]=local_components
//                      [4]=root0 [5]=border_links
//   c[32+t] = binarize threshold bits (line 2, read-only during k_ccl)

__global__ void k_zero(uint32_t* c) {
    c[0]  = 0x7F800000u; c[1]  = 0; c[2]  = 0; c[3]  = 0; c[4]  = 0; c[5]  = 0;
    c[16] = 0x7F800000u; c[17] = 0; c[18] = 0; c[19] = 0; c[20] = 0; c[21] = 0;
    c[32] = 0; c[33] = 0;
}

// ---- fused opening (cross erode+dilate) + per-input min/max, row-sweep -----
__global__ void k_open(const float* __restrict__ in0, const float* __restrict__ in1,
                       float* __restrict__ out0, float* __restrict__ out1,
                       uint32_t* cbase) {
    int t6 = blockIdx.x >> 9;            // input index
    int r  = blockIdx.x & 511;
    int b  = r >> 7;
    int y0 = (r & 127) * RS;
    int t  = threadIdx.x;
    const float* in = t6 ? in1 : in0;
    float* out      = t6 ? out1 : out0;
    uint32_t* c     = cbase + t6 * 16;
    const float4* inb = (const float4*)(in + (size_t)b * HW);
    float4* outb      = (float4*)(out + (size_t)b * HW);

    float4 A[RS + 4];
    #pragma unroll
    for (int j = 0; j < RS + 4; j++) {
        int iy = y0 - 2 + j;
        if (iy >= 0 && iy < HH) A[j] = inb[iy * 256 + t];
        else A[j] = make_float4(1e10f, 1e10f, 1e10f, 1e10f);  // erosion pad
    }

    __shared__ float sx[RS + 2][258];
    __shared__ float sw[RS + 2][258];
    #pragma unroll
    for (int rr = 0; rr < RS + 2; rr++) { sx[rr][t + 1] = A[rr + 1].x; sw[rr][t + 1] = A[rr + 1].w; }
    if (t < RS + 2) { sw[t][0] = 1e10f; sx[t][257] = 1e10f; }
    __syncthreads();

    float4 E[RS + 2];
    #pragma unroll
    for (int rr = 0; rr < RS + 2; rr++) {
        int ey = y0 - 1 + rr;
        float lw = sw[rr][t], rw = sx[rr][t + 2];
        float4 v = A[rr + 1];
        float hx = fminf(fminf(lw, v.x), v.y);
        float hy = fminf(fminf(v.x, v.y), v.z);
        float hz = fminf(fminf(v.y, v.z), v.w);
        float hw = fminf(fminf(v.z, v.w), rw);
        float4 e;
        e.x = fminf(hx, fminf(A[rr].x, A[rr + 2].x));
        e.y = fminf(hy, fminf(A[rr].y, A[rr + 2].y));
        e.z = fminf(hz, fminf(A[rr].z, A[rr + 2].z));
        e.w = fminf(hw, fminf(A[rr].w, A[rr + 2].w));
        if (ey < 0 || ey >= HH) e = make_float4(-1e10f, -1e10f, -1e10f, -1e10f);
        E[rr] = e;
    }
    __syncthreads();

    #pragma unroll
    for (int d = 0; d < RS; d++) { sx[d][t + 1] = E[d + 1].x; sw[d][t + 1] = E[d + 1].w; }
    if (t < RS) { sw[t][0] = -1e10f; sx[t][257] = -1e10f; }
    __syncthreads();

    float lmin = __uint_as_float(0x7F800000u);
    float lmax = 0.0f;
    #pragma unroll
    for (int d = 0; d < RS; d++) {
        float lw = sw[d][t], rw = sx[d][t + 2];
        float4 v = E[d + 1];
        float hx = fmaxf(fmaxf(lw, v.x), v.y);
        float hy = fmaxf(fmaxf(v.x, v.y), v.z);
        float hz = fmaxf(fmaxf(v.y, v.z), v.w);
        float hw = fmaxf(fmaxf(v.z, v.w), rw);
        float4 o;
        o.x = fmaxf(hx, fmaxf(E[d].x, E[d + 2].x));
        o.y = fmaxf(hy, fmaxf(E[d].y, E[d + 2].y));
        o.z = fmaxf(hz, fmaxf(E[d].z, E[d + 2].z));
        o.w = fmaxf(hw, fmaxf(E[d].w, E[d + 2].w));
        outb[(y0 + d) * 256 + t] = o;
        lmin = fminf(lmin, fminf(fminf(o.x, o.y), fminf(o.z, o.w)));
        lmax = fmaxf(lmax, fmaxf(fmaxf(o.x, o.y), fmaxf(o.z, o.w)));
    }
    for (int off = 32; off > 0; off >>= 1) {
        lmin = fminf(lmin, __shfl_down(lmin, off));
        lmax = fmaxf(lmax, __shfl_down(lmax, off));
    }
    __shared__ float smin[4], smax[4];
    if ((t & 63) == 0) { smin[t >> 6] = lmin; smax[t >> 6] = lmax; }
    __syncthreads();
    if (t == 0) {
        float m0 = fminf(fminf(smin[0], smin[1]), fminf(smin[2], smin[3]));
        float m1 = fmaxf(fmaxf(smax[0], smax[1]), fmaxf(smax[2], smax[3]));
        atomicMin(&c[0], __float_as_uint(m0));  // non-negative floats: bit order == float order
        atomicMax(&c[1], __float_as_uint(m1));
    }
}

// ---- exact binarize threshold: smallest float B with (B-mn)/denom >= 0.5 ---
// Predicate is monotone in the (non-negative) float bit pattern, so v >= B
// is bitwise identical to the reference's ((v-mn)/denom >= 0.5) for every v.
__global__ void k_thresh(uint32_t* c) {
    int t6 = threadIdx.x;
    if (t6 >= 2) return;
    float mn = __uint_as_float(c[t6 * 16 + 0]);
    float mx = __uint_as_float(c[t6 * 16 + 1]);
    float denom = (mx - mn) + 1e-10f;   // reference association order
    uint32_t lo = 0, hi = 0x7F800000u;  // +0 .. +inf ((inf-mn)/denom = inf >= 0.5)
    while (lo < hi) {
        uint32_t mid = (lo + hi) >> 1;
        float q = (__uint_as_float(mid) - mn) / denom;  // IEEE f32 div
        if (q >= 0.5f) hi = mid; else lo = mid + 1;
    }
    c[32 + t6] = lo;
}

// ---------------- LDS union-find (workgroup scope) --------------------------
__device__ __forceinline__ uint32_t lload(uint32_t* lp, uint32_t x) {
    return __hip_atomic_load(&lp[x], __ATOMIC_RELAXED, __HIP_MEMORY_SCOPE_WORKGROUP);
}
__device__ __forceinline__ uint32_t lfind(uint32_t* lp, uint32_t x) {
    uint32_t p = lload(lp, x);
    while (p != x) {
        uint32_t gp = lload(lp, p);
        if (gp != p)
            __hip_atomic_store(&lp[x], gp, __ATOMIC_RELAXED, __HIP_MEMORY_SCOPE_WORKGROUP);
        x = p; p = gp;
    }
    return x;
}
// returns 1 iff this call performed the successful root-killing CAS
__device__ uint32_t lunion(uint32_t* lp, uint32_t a, uint32_t b) {
    uint32_t ra = lfind(lp, a), rb = lfind(lp, b);
    while (ra != rb) {
        uint32_t hi = ra > rb ? ra : rb;
        uint32_t lo = ra ^ rb ^ hi;
        uint32_t old = atomicCAS(&lp[lo], lo, hi);
        if (old == lo) return 1;
        ra = lfind(lp, old);
        rb = lfind(lp, hi);
    }
    return 0;
}

__device__ __forceinline__ int run_len(uint32_t bits) {  // consecutive 1s from bit 0
    return (int)__builtin_ctzll(~(uint64_t)bits);        // safe for bits==0xFFFFFFFF
}

// ---------------- binarize + tile-local run-based CCL (both inputs) ---------
// P[i] = global index of tile-local component max, INVALID if bg.
// In-place: P aliases opened (all tile reads complete before stores).
__global__ void k_ccl(const float* __restrict__ op0, const float* __restrict__ op1,
                      uint32_t* __restrict__ P0, uint32_t* __restrict__ P1,
                      uint32_t* cbase) {
    int t6 = blockIdx.x >> 12;
    int tile = blockIdx.x & 4095;
    const float* opened = t6 ? op1 : op0;
    uint32_t* P = t6 ? P1 : P0;
    uint32_t* c = cbase + t6 * 16;
    float thr = __uint_as_float(cbase[32 + t6]);  // exact boundary (read-only line)

    int b  = tile >> 10;
    int tt = tile & 1023;
    int ty0 = (tt >> 5) << 5;
    int tx0 = (tt & 31) << 5;
    uint32_t base = (uint32_t)b * HW + (uint32_t)ty0 * WW + tx0;

    __shared__ uint32_t m[32];
    __shared__ uint32_t lp[1024];
    int trow = threadIdx.x >> 3;        // 0..31
    int tc4  = (threadIdx.x & 7) << 2;  // 0,4,..,28
    const float4* op4 = (const float4*)(opened + base);
    float4 v = op4[trow * 256 + (tc4 >> 2)];
    uint32_t m0 = (v.x >= thr) ? 1u : 0u;   // == ((v-mn)/denom >= 0.5) bitwise
    uint32_t m1 = (v.y >= thr) ? 1u : 0u;
    uint32_t m2 = (v.z >= thr) ? 1u : 0u;
    uint32_t m3 = (v.w >= thr) ? 1u : 0u;
    uint32_t fgcnt = m0 + m1 + m2 + m3;
    uint32_t rowm = (m0 | (m1 << 1) | (m2 << 2) | (m3 << 3)) << tc4;
    rowm |= __shfl_xor(rowm, 1, 8);     // 8 lanes per row
    rowm |= __shfl_xor(rowm, 2, 8);
    rowm |= __shfl_xor(rowm, 4, 8);
    if ((threadIdx.x & 7) == 0) m[trow] = rowm;
    int li0 = (trow << 5) + tc4;
    *(uint4*)&lp[li0] = make_uint4(li0, li0 + 1, li0 + 2, li0 + 3);
    __syncthreads();

    // unions at run-start pixels, one per overlapping run in the row above
    uint32_t links = 0;
    if (trow > 0 && rowm) {
        uint32_t up = m[trow - 1];
        #pragma unroll
        for (int j = 0; j < 4; j++) {
            int lx = tc4 + j;
            if (!((rowm >> lx) & 1u)) continue;
            if (lx > 0 && ((rowm >> (lx - 1)) & 1u)) continue;  // not run start
            int len = run_len(rowm >> lx);
            int e = lx + len - 1;
            int lo = (lx == 0) ? 0 : lx - 1;
            int hi = (e >= 31) ? 31 : e + 1;
            uint32_t hm = (hi == 31) ? 0xFFFFFFFFu : ((1u << (hi + 1)) - 1u);
            uint32_t w = up & hm & ~((1u << lo) - 1u);
            uint32_t repA = ((uint32_t)trow << 5) + e;
            while (w) {
                int xs = __builtin_ctz(w);
                int xe = xs + run_len(up >> xs) - 1;  // rep of the run above
                links += lunion(lp, repA, ((uint32_t)(trow - 1) << 5) + (uint32_t)xe);
                w = (xe >= 31) ? 0u : (w & ~((1u << (xe + 1)) - 1u));
            }
        }
    }
    __syncthreads();

    // pixel-0 / label-0 case: decidable here (all its neighbors intra-tile)
    if (tile == 0 && threadIdx.x == 0) {
        if ((rowm & 1u) && !(rowm & 2u) && lp[0] == 0u) atomicOr(&c[4], 1u);
    }

    // flatten: pixel -> root of its run rep; full coalesced uint4 store
    uint4 g;
    uint32_t* gp = &g.x;
    int laste = -1; uint32_t lastg = 0;
    #pragma unroll
    for (int j = 0; j < 4; j++) {
        int lx = tc4 + j;
        if (!((rowm >> lx) & 1u)) { gp[j] = INVALID; continue; }
        int e = lx + run_len(rowm >> lx) - 1;
        if (e == laste) { gp[j] = lastg; continue; }
        uint32_t r = lfind(lp, ((uint32_t)trow << 5) + (uint32_t)e);
        lastg = base + (r >> 5) * WW + (r & 31);
        laste = e;
        gp[j] = lastg;
    }
    *(uint4*)(P + base + (uint32_t)trow * WW + tc4) = g;

    // packed block reduction: fg(12b) | runs(10b) | links(10b)
    uint32_t runs = ((threadIdx.x & 7) == 0) ? (uint32_t)__popc(rowm & ~(rowm << 1)) : 0u;
    uint32_t pk = (fgcnt << 20) | (runs << 10) | links;
    for (int off = 32; off > 0; off >>= 1) pk += __shfl_down(pk, off);
    __shared__ uint32_t s[4];
    if ((threadIdx.x & 63) == 0) s[threadIdx.x >> 6] = pk;
    __syncthreads();
    if (threadIdx.x == 0) {
        uint32_t sum = s[0] + s[1] + s[2] + s[3];
        uint32_t fgs = sum >> 20, rns = (sum >> 10) & 1023u, lks = sum & 1023u;
        if (fgs) atomicAdd(&c[2], fgs);
        if (rns - lks) atomicAdd(&c[3], rns - lks);  // tile-local component count
    }
}

// ---------------- global union-find (device scope, cross-XCD safe) ----------
__device__ __forceinline__ uint32_t pload(uint32_t* P, uint32_t x) {
    return __hip_atomic_load(&P[x], __ATOMIC_RELAXED, __HIP_MEMORY_SCOPE_AGENT);
}
__device__ __forceinline__ uint32_t uf_find(uint32_t* P, uint32_t x) {
    uint32_t p = pload(P, x);
    while (p != x) {
        uint32_t gp = pload(P, p);
        if (gp != p)
            __hip_atomic_store(&P[x], gp, __ATOMIC_RELAXED, __HIP_MEMORY_SCOPE_AGENT);
        x = p; p = gp;
    }
    return x;
}
__device__ uint32_t uf_union(uint32_t* P, uint32_t a, uint32_t b) {
    uint32_t ra = uf_find(P, a);
    uint32_t rb = uf_find(P, b);
    while (ra != rb) {
        uint32_t hi = ra > rb ? ra : rb;
        uint32_t lo = ra ^ rb ^ hi;
        uint32_t old = atomicCAS(&P[lo], lo, hi);
        if (old == lo) return 1;  // killed exactly one root
        ra = uf_find(P, old);
        rb = uf_find(P, hi);
    }
    return 0;
}

// border pixels only, both inputs: 96 candidates/tile (lx==0, lx==31, ly==31)
__global__ void k_border(uint32_t* P0, uint32_t* P1, uint32_t* cbase) {
    int t6 = (blockIdx.x >= 1536);
    uint32_t* P = t6 ? P1 : P0;
    uint32_t* c = cbase + t6 * 16;
    int tid = (blockIdx.x - (t6 ? 1536 : 0)) * 256 + threadIdx.x;
    int tile = tid / 96;
    int k = tid - tile * 96;
    int b  = tile >> 10;
    int tt = tile & 1023;
    int ty0 = (tt >> 5) << 5;
    int tx0 = (tt & 31) << 5;
    int g = k >> 5, o = k & 31;
    int ly, lx;
    if (g == 0)      { ly = o;  lx = 0; }
    else if (g == 1) { ly = o;  lx = 31; }
    else             { ly = 31; lx = o; }   // corners duplicated: CAS-unique, count safe
    int x = tx0 + lx, y = ty0 + ly;
    int i = b * HW + y * WW + x;
    uint32_t links = 0;
    if (P[i] != INVALID) {
        bool xe = (x < WW - 1), ys = (y < HH - 1);
        if (lx == 31 && xe && P[i + 1] != INVALID) links += uf_union(P, i, i + 1);
        if (ys) {
            bool cS = (ly == 31);
            if (cS && P[i + WW] != INVALID)                            links += uf_union(P, i, i + WW);
            if ((cS || lx == 0)  && x > 0 && P[i + WW - 1] != INVALID) links += uf_union(P, i, i + WW - 1);
            if ((cS || lx == 31) && xe    && P[i + WW + 1] != INVALID) links += uf_union(P, i, i + WW + 1);
        }
    }
    for (int off = 32; off > 0; off >>= 1) links += __shfl_down(links, off);
    __shared__ uint32_t s[4];
    if ((threadIdx.x & 63) == 0) s[threadIdx.x >> 6] = links;
    __syncthreads();
    if (threadIdx.x == 0) {
        uint32_t sum = s[0] + s[1] + s[2] + s[3];
        if (sum) atomicAdd(&c[5], sum);
    }
}

__global__ void k_final(const uint32_t* __restrict__ c, float* __restrict__ out) {
    uint32_t nf0 = c[2],  lc0 = c[3],  z0 = c[4],  gl0 = c[5];
    uint32_t nf1 = c[18], lc1 = c[19], z1 = c[20], gl1 = c[21];
    uint32_t roots0 = lc0 - gl0;   // final roots (incl. a pixel-0 singleton)
    uint32_t roots1 = lc1 - gl1;
    float ccs  = (float)(roots0 - z0 + ((nf0 < (uint32_t)NPIX || z0) ? 1u : 0u));
    float ccsg = (float)(roots1 - z1 + ((nf1 < (uint32_t)NPIX || z1) ? 1u : 0u));
    out[0] = fabsf(ccsg - ccs) / (float)nf1;   // all exact ints < 2^24
}

extern "C" void kernel_launch(void* const* d_in, const int* in_sizes, int n_in,
                              void* d_out, int out_size, void* d_ws, size_t ws_size,
                              hipStream_t stream) {
    const float* img = (const float*)d_in[0];
    const float* lab = (const float*)d_in[1];
    float* out = (float*)d_out;
    char* ws = (char*)d_ws;

    float* buf0 = (float*)ws;                                   // 16 MB img: opened -> P (in place)
    float* buf1 = (float*)(ws + (size_t)NPIX * sizeof(float));  // 16 MB lab: opened -> P
    uint32_t* cnt = (uint32_t*)(ws + (size_t)2 * NPIX * sizeof(float));
    uint32_t* P0 = (uint32_t*)buf0;
    uint32_t* P1 = (uint32_t*)buf1;

    k_zero<<<1, 1, 0, stream>>>(cnt);
    k_open<<<2 * NB * (HH / RS), 256, 0, stream>>>(img, lab, buf0, buf1, cnt);
    k_thresh<<<1, 64, 0, stream>>>(cnt);
    k_ccl<<<2 * NTILES, 256, 0, stream>>>(buf0, buf1, P0, P1, cnt);
    k_border<<<2 * (NTILES * 96) / 256, 256, 0, stream>>>(P0, P1, cnt);
    k_final<<<1, 1, 0, stream>>>(cnt, out);
}